// Round 8
// baseline (23582.426 us; speedup 1.0000x reference)
//
#include <hip/hip_runtime.h>
#include <hip/hip_bf16.h>
#include <math.h>

// AtlasLayerBlock: B=4,S=4096,D=1024, chunked scan (64 chunks), rank-192
// Newton-Schulz in 192x192 Gram space (exact algebra). Big GEMMs: bf16 MFMA.
// [Round 7: round-6 kernel + ws_size guard. If ws_size < required (~170 MiB),
//  launch NOTHING -> bench fails with the distinctive empty-output absmax
//  (~29.25) instead of a core dump, separating "ws too small" from
//  "in-kernel fault" in one bench. Branch is deterministic -> graph-safe.]

#define DEV __device__ __forceinline__

typedef __bf16 bf16x8 __attribute__((ext_vector_type(8)));
typedef float f32x4 __attribute__((ext_vector_type(4)));
typedef unsigned short us4 __attribute__((ext_vector_type(4)));
typedef unsigned short us8 __attribute__((ext_vector_type(8)));

constexpr int Bb = 4, Ss = 4096, Dd = 1024, CHK = 64, WIN = 128, NCh = 64, CTX = 192;
constexpr int SEXT = Ss + WIN;      // 4224
constexpr int CS = CTX * CTX;       // 36864
constexpr int CCH = 16;             // conv in-place chunk rows
constexpr int NCCH = Ss / CCH;      // 256
constexpr float EPSf = 1e-6f;
constexpr float NSa = 3.4445f, NSb = -4.775f, NSc = 2.0315f;

DEV float bf2f(unsigned short u) { union { unsigned int i; float f; } v; v.i = ((unsigned int)u) << 16; return v.f; }
DEV unsigned short f2bf(float f) {
  union { unsigned int i; float f; } v; v.f = f;
  unsigned int i = v.i;
  return (unsigned short)((i + 0x7FFFu + ((i >> 16) & 1u)) >> 16);
}
DEV float siluf(float x) { return x / (1.f + expf(-x)); }

DEV float block_sum256(float v) {
  __shared__ float red[256];
  int t = threadIdx.x;
  red[t] = v; __syncthreads();
  for (int s = 128; s > 0; s >>= 1) { if (t < s) red[t] += red[t + s]; __syncthreads(); }
  return red[0];
}

// ---------- MFMA 64x64 tile: C[m][n] = sum_k A[m][k]*Bt[n][k]. 4 waves (2x2 of 32x32).
DEV void mfma_tile64(const unsigned short* __restrict__ A, int lda,
                     const unsigned short* __restrict__ Bt, int ldb,
                     int K, f32x4 acc[2][2]) {
  int lane = threadIdx.x & 63;
  int w = threadIdx.x >> 6;
  int wr = (w >> 1) & 1, wc = w & 1;
  int lr = lane & 15, lk = (lane >> 4) << 3;
  const unsigned short* a0p = A + (size_t)(wr * 32 + lr) * lda + lk;
  const unsigned short* a1p = a0p + (size_t)16 * lda;
  const unsigned short* b0p = Bt + (size_t)(wc * 32 + lr) * ldb + lk;
  const unsigned short* b1p = b0p + (size_t)16 * ldb;
  for (int k = 0; k < K; k += 32) {
    bf16x8 a0 = *(const bf16x8*)(a0p + k);
    bf16x8 a1 = *(const bf16x8*)(a1p + k);
    bf16x8 b0 = *(const bf16x8*)(b0p + k);
    bf16x8 b1 = *(const bf16x8*)(b1p + k);
    acc[0][0] = __builtin_amdgcn_mfma_f32_16x16x32_bf16(a0, b0, acc[0][0], 0, 0, 0);
    acc[0][1] = __builtin_amdgcn_mfma_f32_16x16x32_bf16(a0, b1, acc[0][1], 0, 0, 0);
    acc[1][0] = __builtin_amdgcn_mfma_f32_16x16x32_bf16(a1, b0, acc[1][0], 0, 0, 0);
    acc[1][1] = __builtin_amdgcn_mfma_f32_16x16x32_bf16(a1, b1, acc[1][1], 0, 0, 0);
  }
}
DEV void zero_acc(f32x4 acc[2][2]) {
  f32x4 z = {0.f, 0.f, 0.f, 0.f};
  acc[0][0] = z; acc[0][1] = z; acc[1][0] = z; acc[1][1] = z;
}

// ---------- f32 NT 32x32 tile core
DEV void nt32_tile(const float* __restrict__ A, int lda,
                   const float* __restrict__ Bm, int ldb,
                   int K, int m0, int n0, float acc[2][2]) {
  __shared__ float As[32][17], Bs[32][17];
  int tid = threadIdx.x;
  int ty = tid >> 4, tx = tid & 15;
  int r = tid >> 3, c = (tid & 7) * 2;
  for (int k0 = 0; k0 < K; k0 += 16) {
    float2 av = *(const float2*)(A + (size_t)(m0 + r) * lda + k0 + c);
    float2 bv = *(const float2*)(Bm + (size_t)(n0 + r) * ldb + k0 + c);
    __syncthreads();
    As[r][c] = av.x; As[r][c + 1] = av.y;
    Bs[r][c] = bv.x; Bs[r][c + 1] = bv.y;
    __syncthreads();
#pragma unroll
    for (int kk = 0; kk < 16; ++kk) {
      float a0 = As[ty * 2][kk], a1 = As[ty * 2 + 1][kk];
      float b0 = Bs[tx * 2][kk], b1 = Bs[tx * 2 + 1][kk];
      acc[0][0] += a0 * b0; acc[0][1] += a0 * b1;
      acc[1][0] += a1 * b0; acc[1][1] += a1 * b1;
    }
  }
}

// =================== pre-stage ===================

__global__ __launch_bounds__(256) void rmsin_kernel(const float* __restrict__ x,
                                                    const float* __restrict__ w,
                                                    unsigned short* __restrict__ xn) {
  size_t row = blockIdx.x;
  const float* xr = x + row * Dd;
  int t = threadIdx.x;
  f32x4 v = *(const f32x4*)(xr + t * 4);
  float ss = v[0] * v[0] + v[1] * v[1] + v[2] * v[2] + v[3] * v[3];
  ss = block_sum256(ss);
  float sc = rsqrtf(ss * (1.f / Dd) + EPSf);
  f32x4 wv = *(const f32x4*)(w + t * 4);
  unsigned short* o = xn + row * Dd + t * 4;
  o[0] = f2bf(v[0] * sc * wv[0]); o[1] = f2bf(v[1] * sc * wv[1]);
  o[2] = f2bf(v[2] * sc * wv[2]); o[3] = f2bf(v[3] * sc * wv[3]);
}

__global__ __launch_bounds__(256) void packw_kernel(const float* __restrict__ Wk, const float* __restrict__ Wq,
                                                    const float* __restrict__ Wv, const float* __restrict__ Wg,
                                                    const float* __restrict__ Wb, unsigned short* __restrict__ Wall) {
  size_t idx = (size_t)blockIdx.x * 256 + threadIdx.x; // 7168*1024
  int j = (int)(idx >> 10), c = (int)(idx & 1023);
  int seg = j >> 10;
  const float* src;
  if (seg == 0) src = Wk + ((size_t)j << 10);
  else if (seg == 1) src = Wq + ((size_t)(j - 1024) << 10);
  else if (seg == 2) src = Wv + ((size_t)(j - 2048) << 10);
  else if (seg < 6) src = Wg + ((size_t)(j - 3072) << 10);
  else src = Wb + ((size_t)(j - 6144) << 10);
  Wall[idx] = f2bf(src[c]);
}

__global__ __launch_bounds__(256) void init_ext_kernel(const float* __restrict__ bufk, const float* __restrict__ bufv,
                                                       unsigned short* __restrict__ kext, unsigned short* __restrict__ vext) {
  size_t idx = (size_t)blockIdx.x * 256 + threadIdx.x; // B*WIN*D
  int b = (int)(idx >> 17); size_t rem = idx & 131071;
  kext[((size_t)b * SEXT) * Dd + rem] = f2bf(bufk[idx]);
  vext[((size_t)b * SEXT) * Dd + rem] = f2bf(bufv[idx]);
}

__global__ __launch_bounds__(256) void init_mt_kernel(const float* __restrict__ mem,
                                                      float* __restrict__ Mtf, unsigned short* __restrict__ Mtb) {
  size_t idx = (size_t)blockIdx.x * 256 + threadIdx.x; // B*D*D
  int b = (int)(idx >> 20); size_t rem = idx & 1048575;
  int j = (int)(rem >> 10), i = (int)(rem & 1023);
  float v = mem[((size_t)b << 20) + ((size_t)i << 10) + j]; // Mt[j][i] = M[i][j]
  Mtf[idx] = v; Mtb[idx] = f2bf(v);
}

__global__ void zero_nrm_kernel(float* __restrict__ nrm2) { nrm2[threadIdx.x] = 0.f; }

// projections segs 0..5: [kraw->kext | qraw->qb | v->vext | gamma->gb | eta | alpha]
__global__ __launch_bounds__(256) void proj_kernel(const unsigned short* __restrict__ xn,
                                                   const unsigned short* __restrict__ Wall,
                                                   unsigned short* __restrict__ kext, unsigned short* __restrict__ qb,
                                                   unsigned short* __restrict__ vext, unsigned short* __restrict__ gb,
                                                   float* __restrict__ etam, float* __restrict__ alm) {
  int m0 = blockIdx.y * 64, n0 = blockIdx.x * 64;
  f32x4 acc[2][2]; zero_acc(acc);
  mfma_tile64(xn + (size_t)m0 * Dd, Dd, Wall + (size_t)n0 * Dd, Dd, Dd, acc);
  int seg = n0 >> 10;
  __shared__ float colsum[64];
  bool is_mean = (seg == 4 || seg == 5);
  if (is_mean) { if (threadIdx.x < 64) colsum[threadIdx.x] = 0.f; __syncthreads(); }
  int lane = threadIdx.x & 63, w = threadIdx.x >> 6;
  int wr = (w >> 1) & 1, wc = w & 1;
  int l4 = (lane >> 4) << 2, lc = lane & 15;
  for (int mr = 0; mr < 2; ++mr)
    for (int nc = 0; nc < 2; ++nc)
      for (int i = 0; i < 4; ++i) {
        int rl = wr * 32 + mr * 16 + l4 + i;
        int cl = wc * 32 + nc * 16 + lc;
        float v = acc[mr][nc][i];
        int rg = m0 + rl, cl1 = (n0 + cl) & 1023;
        int bb = rg >> 12, s2 = rg & 4095;
        if (seg == 0) kext[((size_t)bb * SEXT + WIN + s2) * Dd + cl1] = f2bf(v);
        else if (seg == 1) qb[(size_t)rg * Dd + cl1] = f2bf(v);
        else if (seg == 2) vext[((size_t)bb * SEXT + WIN + s2) * Dd + cl1] = f2bf(siluf(v));
        else if (seg == 3) gb[(size_t)rg * Dd + cl1] = f2bf(siluf(v));
        else atomicAdd(&colsum[cl], siluf(v));
      }
  if (is_mean) {
    __syncthreads();
    if (threadIdx.x < 64) {
      int bb = m0 >> 12, tt = (m0 & 4095) >> 6;
      int cl1 = (n0 & 1023) + threadIdx.x;
      float* dst = (seg == 4) ? etam : alm;
      dst[((size_t)bb * NCh + tt) * Dd + cl1] = colsum[threadIdx.x] * (1.f / 64.f);
    }
  }
}

// bypass GEMM: gb *= silu(xn @ Wb^T)  (Wb = Wall rows [6144,7168))
__global__ __launch_bounds__(256) void bypmul_kernel(const unsigned short* __restrict__ xn,
                                                     const unsigned short* __restrict__ Wall,
                                                     unsigned short* __restrict__ gb) {
  int m0 = blockIdx.y * 64, n0 = blockIdx.x * 64;
  f32x4 acc[2][2]; zero_acc(acc);
  mfma_tile64(xn + (size_t)m0 * Dd, Dd, Wall + (size_t)(6144 + n0) * Dd, Dd, Dd, acc);
  int lane = threadIdx.x & 63, w = threadIdx.x >> 6;
  int wr = (w >> 1) & 1, wc = w & 1;
  int l4 = (lane >> 4) << 2, lc = lane & 15;
  for (int mr = 0; mr < 2; ++mr)
    for (int nc = 0; nc < 2; ++nc)
      for (int i = 0; i < 4; ++i) {
        int rg = m0 + wr * 32 + mr * 16 + l4 + i;
        int cc = n0 + wc * 32 + nc * 16 + lc;
        size_t idx = (size_t)rg * Dd + cc;
        gb[idx] = f2bf(bf2f(gb[idx]) * siluf(acc[mr][nc][i]));
      }
}

// save 16-row-chunk boundary rows of raw k/q before in-place conv.
// halo[b][tens][n][which][col], which 0=first row (n*16), 1=last row (n*16+15)
__global__ __launch_bounds__(256) void halo_kernel(const unsigned short* __restrict__ kext,
                                                   const unsigned short* __restrict__ qb,
                                                   unsigned short* __restrict__ halo) {
  size_t idx = (size_t)blockIdx.x * 256 + threadIdx.x; // 4*2*256*2*1024
  int col = (int)(idx & 1023);
  int which = (int)((idx >> 10) & 1);
  int n = (int)((idx >> 11) & 255);
  int tens = (int)((idx >> 19) & 1);
  int b = (int)(idx >> 20);
  int s = n * CCH + (which ? (CCH - 1) : 0);
  unsigned short v = tens ? qb[((size_t)b * Ss + s) * Dd + col]
                          : kext[((size_t)b * SEXT + WIN + s) * Dd + col];
  halo[idx] = v;
}

// in-place depthwise conv3 + silu + rmsnorm over 16-row chunks (LDS staged).
__global__ __launch_bounds__(256) void conv_ip_kernel(unsigned short* __restrict__ kext,
                                                      unsigned short* __restrict__ qb,
                                                      const unsigned short* __restrict__ halo,
                                                      const float* __restrict__ ckw, const float* __restrict__ ckb,
                                                      const float* __restrict__ cqw, const float* __restrict__ cqb,
                                                      const float* __restrict__ wkq) {
  int n = blockIdx.x, tens = blockIdx.y, b = blockIdx.z;
  unsigned short* base = tens ? (qb + ((size_t)b * Ss + (size_t)n * CCH) * Dd)
                              : (kext + ((size_t)b * SEXT + WIN + (size_t)n * CCH) * Dd);
  __shared__ unsigned short L[CCH + 2][Dd];
  int tid = threadIdx.x;
  // main rows -> LDS rows 1..16
#pragma unroll
  for (int i = 0; i < CCH; ++i)
    *(us4*)&L[i + 1][tid * 4] = *(const us4*)(base + (size_t)i * Dd + tid * 4);
  // halo rows (prev chunk's last, next chunk's first); zeros at sequence ends
  us4 z = {0, 0, 0, 0};
  us4 h0 = (n == 0) ? z
    : *(const us4*)(halo + ((((size_t)b * 2 + tens) * NCCH + (n - 1)) * 2 + 1) * Dd + tid * 4);
  *(us4*)&L[0][tid * 4] = h0;
  us4 h1 = (n == NCCH - 1) ? z
    : *(const us4*)(halo + ((((size_t)b * 2 + tens) * NCCH + (n + 1)) * 2 + 0) * Dd + tid * 4);
  *(us4*)&L[CCH + 1][tid * 4] = h1;
  __syncthreads();
  const float* cw = tens ? cqw : ckw;
  const float* cb = tens ? cqb : ckb;
  int wave = tid >> 6, lane = tid & 63;
  int c0 = lane * 16;
#pragma unroll
  for (int j = 0; j < 4; ++j) {
    int r = wave * 4 + j;
    float y[16]; float ss = 0.f;
#pragma unroll
    for (int i = 0; i < 16; ++i) {
      int d = c0 + i;
      float xm = bf2f(L[r][d]), xc = bf2f(L[r + 1][d]), xp = bf2f(L[r + 2][d]);
      float v = xm * cw[d * 3] + xc * cw[d * 3 + 1] + xp * cw[d * 3 + 2] + cb[d];
      v = siluf(v);
      y[i] = v; ss += v * v;
    }
#pragma unroll
    for (int off = 1; off < 64; off <<= 1) ss += __shfl_xor(ss, off);
    float sc = rsqrtf(ss * (1.f / Dd) + EPSf);
    us8 o0, o1;
#pragma unroll
    for (int i = 0; i < 8; ++i) {
      o0[i] = f2bf(y[i] * sc * wkq[c0 + i]);
      o1[i] = f2bf(y[8 + i] * sc * wkq[c0 + 8 + i]);
    }
    *(us8*)(base + (size_t)r * Dd + c0) = o0;
    *(us8*)(base + (size_t)r * Dd + c0 + 8) = o1;
  }
}

// =================== per-chunk kernels ===================

// err = ctx_k @ M - ctx_v   (M=192,N=1024,K=1024); V is bf16
__global__ __launch_bounds__(256) void err_kernel(const unsigned short* __restrict__ kext,
                                                  const unsigned short* __restrict__ Mtb,
                                                  const unsigned short* __restrict__ vext,
                                                  float* __restrict__ errf, int t) {
  int b = blockIdx.z;
  int m0 = blockIdx.y * 64, n0 = blockIdx.x * 64;
  const unsigned short* A = kext + ((size_t)b * SEXT + (size_t)t * CHK + m0) * Dd;
  const unsigned short* Bt = Mtb + ((size_t)b << 20) + (size_t)n0 * Dd;
  f32x4 acc[2][2]; zero_acc(acc);
  mfma_tile64(A, Dd, Bt, Dd, Dd, acc);
  const unsigned short* V = vext + ((size_t)b * SEXT + (size_t)t * CHK) * Dd;
  float* Ep = errf + (size_t)b * CTX * Dd;
  int lane = threadIdx.x & 63, w = threadIdx.x >> 6;
  int wr = (w >> 1) & 1, wc = w & 1;
  int l4 = (lane >> 4) << 2, lc = lane & 15;
  for (int mr = 0; mr < 2; ++mr)
    for (int nc = 0; nc < 2; ++nc)
      for (int i = 0; i < 4; ++i) {
        int rr = m0 + wr * 32 + mr * 16 + l4 + i;
        int cc = n0 + wc * 32 + nc * 16 + lc;
        Ep[(size_t)rr * Dd + cc] = acc[mr][nc][i] - bf2f(V[(size_t)rr * Dd + cc]);
      }
}

// T = K K^T ; S_E = E E^T ; nrm2 += sum(T*S_E)
__global__ __launch_bounds__(256) void tnorm_kernel(const unsigned short* __restrict__ kext,
                                                    const float* __restrict__ errf,
                                                    float* __restrict__ Tb, float* __restrict__ Sb,
                                                    float* __restrict__ nrm2, int t) {
  int b = blockIdx.z;
  const unsigned short* K = kext + ((size_t)b * SEXT + (size_t)t * CHK) * Dd;
  const float* E = errf + (size_t)b * CTX * Dd;
  int m0 = blockIdx.y * 32, n0 = blockIdx.x * 32;
  __shared__ float Ka[32][17], Kb2[32][17], Ea[32][17], Eb[32][17];
  float accT[2][2] = {{0, 0}, {0, 0}}, accS[2][2] = {{0, 0}, {0, 0}};
  int tid = threadIdx.x, ty = tid >> 4, tx = tid & 15;
  int r = tid >> 3, c = (tid & 7) * 2;
  for (int k0 = 0; k0 < Dd; k0 += 16) {
    unsigned short ka0 = K[(size_t)(m0 + r) * Dd + k0 + c];
    unsigned short ka1 = K[(size_t)(m0 + r) * Dd + k0 + c + 1];
    unsigned short kb0 = K[(size_t)(n0 + r) * Dd + k0 + c];
    unsigned short kb1 = K[(size_t)(n0 + r) * Dd + k0 + c + 1];
    float2 ea = *(const float2*)(E + (size_t)(m0 + r) * Dd + k0 + c);
    float2 eb = *(const float2*)(E + (size_t)(n0 + r) * Dd + k0 + c);
    __syncthreads();
    Ka[r][c] = bf2f(ka0); Ka[r][c + 1] = bf2f(ka1);
    Kb2[r][c] = bf2f(kb0); Kb2[r][c + 1] = bf2f(kb1);
    Ea[r][c] = ea.x; Ea[r][c + 1] = ea.y;
    Eb[r][c] = eb.x; Eb[r][c + 1] = eb.y;
    __syncthreads();
#pragma unroll
    for (int kk = 0; kk < 16; ++kk) {
      float a0 = Ka[ty * 2][kk], a1 = Ka[ty * 2 + 1][kk];
      float b0 = Kb2[tx * 2][kk], b1 = Kb2[tx * 2 + 1][kk];
      accT[0][0] += a0 * b0; accT[0][1] += a0 * b1; accT[1][0] += a1 * b0; accT[1][1] += a1 * b1;
      float c0 = Ea[ty * 2][kk], c1 = Ea[ty * 2 + 1][kk];
      float d0 = Eb[tx * 2][kk], d1 = Eb[tx * 2 + 1][kk];
      accS[0][0] += c0 * d0; accS[0][1] += c0 * d1; accS[1][0] += c1 * d0; accS[1][1] += c1 * d1;
    }
  }
  float local = 0.f;
  float* Tp = Tb + (size_t)b * CS;
  float* Sp = Sb + (size_t)b * CS;
  for (int i = 0; i < 2; ++i)
    for (int j = 0; j < 2; ++j) {
      int mi = m0 + ty * 2 + i, nj = n0 + tx * 2 + j;
      Tp[(size_t)mi * CTX + nj] = accT[i][j];
      Sp[(size_t)mi * CTX + nj] = accS[i][j];
      local += accT[i][j] * accS[i][j];
    }
  float tot = block_sum256(local);
  if (tid == 0) atomicAdd(&nrm2[t * 4 + b], tot);
}

// Kt = K^T (bf16), Et = E^T (bf16)
__global__ __launch_bounds__(256) void trans_ke_kernel(const unsigned short* __restrict__ kext,
                                                       const float* __restrict__ errf,
                                                       unsigned short* __restrict__ Kt,
                                                       unsigned short* __restrict__ Et, int t) {
  int z = blockIdx.z; int b = z >> 1;
  size_t idx = (size_t)blockIdx.x * 256 + threadIdx.x; // < 1024*192
  int i = (int)(idx / CTX); int r = (int)(idx - (size_t)i * CTX);
  if (z & 1) {
    float v = errf[((size_t)b * CTX + r) * Dd + i];
    Et[((size_t)b * Dd + i) * CTX + r] = f2bf(v);
  } else {
    Kt[((size_t)b * Dd + i) * CTX + r] = kext[((size_t)b * SEXT + (size_t)t * CHK + r) * Dd + i];
  }
}

// W = S*T, Wt = T*S
__global__ __launch_bounds__(256) void ns_wwt_kernel(const float* __restrict__ Sb, const float* __restrict__ Tb,
                                                     float* __restrict__ Wb, float* __restrict__ Wtb,
                                                     const float* __restrict__ nrm2, int t, int step) {
  int z = blockIdx.z; int b = z >> 1, which = z & 1;
  int m0 = blockIdx.y * 32, n0 = blockIdx.x * 32;
  const float* A = (which ? Tb : Sb) + (size_t)b * CS;
  const float* Bm = (which ? Sb : Tb) + (size_t)b * CS;
  float acc[2][2] = {{0, 0}, {0, 0}};
  nt32_tile(A, CTX, Bm, CTX, CTX, m0, n0, acc);
  float sc = 1.f;
  if (step == 0) { float n = sqrtf(nrm2[t * 4 + b]) + 1e-7f; sc = 1.f / (n * n); }
  float* C = (which ? Wtb : Wb) + (size_t)b * CS;
  int tid = threadIdx.x, ty = tid >> 4, tx = tid & 15;
  for (int i = 0; i < 2; ++i)
    for (int j = 0; j < 2; ++j)
      C[(size_t)(m0 + ty * 2 + i) * CTX + n0 + tx * 2 + j] = acc[i][j] * sc;
}

// P = a*I + b*W + c*W@W
__global__ __launch_bounds__(256) void ns_p_kernel(const float* __restrict__ Wb, const float* __restrict__ Wtb,
                                                   float* __restrict__ Pb) {
  int b = blockIdx.z;
  int m0 = blockIdx.y * 32, n0 = blockIdx.x * 32;
  float acc[2][2] = {{0, 0}, {0, 0}};
  nt32_tile(Wb + (size_t)b * CS, CTX, Wtb + (size_t)b * CS, CTX, CTX, m0, n0, acc);
  const float* W = Wb + (size_t)b * CS;
  float* P = Pb + (size_t)b * CS;
  int tid = threadIdx.x, ty = tid >> 4, tx = tid & 15;
  for (int i = 0; i < 2; ++i)
    for (int j = 0; j < 2; ++j) {
      int mi = m0 + ty * 2 + i, nj = n0 + tx * 2 + j;
      P[(size_t)mi * CTX + nj] = NSa * ((mi == nj) ? 1.f : 0.f) + NSb * W[(size_t)mi * CTX + nj] + NSc * acc[i][j];
    }
}

// which=0: Z = P S; which=1: Ft' = Ft P^T (step0: Ft'=P^T; step4 writes phi bf16)
__global__ __launch_bounds__(256) void ns_zf_kernel(const float* __restrict__ Pb, const float* __restrict__ Sb,
                                                    const float* __restrict__ Fin, float* __restrict__ Zb,
                                                    float* __restrict__ Fout, unsigned short* __restrict__ phi5,
                                                    const float* __restrict__ nrm2, int t, int step) {
  int z = blockIdx.z; int b, which;
  if (step == 4) { b = z; which = 1; } else { b = z >> 1; which = z & 1; }
  int m0 = blockIdx.y * 32, n0 = blockIdx.x * 32;
  int tid = threadIdx.x, ty = tid >> 4, tx = tid & 15;
  if (which == 0) {
    float acc[2][2] = {{0, 0}, {0, 0}};
    nt32_tile(Pb + (size_t)b * CS, CTX, Sb + (size_t)b * CS, CTX, CTX, m0, n0, acc);
    float sc = 1.f;
    if (step == 0) { float n = sqrtf(nrm2[t * 4 + b]) + 1e-7f; sc = 1.f / (n * n); }
    float* Z = Zb + (size_t)b * CS;
    for (int i = 0; i < 2; ++i)
      for (int j = 0; j < 2; ++j)
        Z[(size_t)(m0 + ty * 2 + i) * CTX + n0 + tx * 2 + j] = acc[i][j] * sc;
  } else {
    float* F = Fout + (size_t)b * CS;
    float vals[2][2];
    if (step == 0) {
      const float* P = Pb + (size_t)b * CS;
      for (int i = 0; i < 2; ++i)
        for (int j = 0; j < 2; ++j)
          vals[i][j] = P[(size_t)(n0 + tx * 2 + j) * CTX + (m0 + ty * 2 + i)];
    } else {
      float acc[2][2] = {{0, 0}, {0, 0}};
      nt32_tile(Fin + (size_t)b * CS, CTX, Pb + (size_t)b * CS, CTX, CTX, m0, n0, acc);
      vals[0][0] = acc[0][0]; vals[0][1] = acc[0][1]; vals[1][0] = acc[1][0]; vals[1][1] = acc[1][1];
    }
    for (int i = 0; i < 2; ++i)
      for (int j = 0; j < 2; ++j) {
        int mi = m0 + ty * 2 + i, nj = n0 + tx * 2 + j;
        F[(size_t)mi * CTX + nj] = vals[i][j];
        if (step == 4) phi5[(size_t)b * CS + (size_t)nj * CTX + mi] = f2bf(vals[i][j]);
      }
  }
}

// S' = P Z
__global__ __launch_bounds__(256) void ns_snew_kernel(const float* __restrict__ Pb, const float* __restrict__ Zb,
                                                      float* __restrict__ Sb) {
  int b = blockIdx.z;
  int m0 = blockIdx.y * 32, n0 = blockIdx.x * 32;
  float acc[2][2] = {{0, 0}, {0, 0}};
  nt32_tile(Pb + (size_t)b * CS, CTX, Zb + (size_t)b * CS, CTX, CTX, m0, n0, acc);
  float* S = Sb + (size_t)b * CS;
  int tid = threadIdx.x, ty = tid >> 4, tx = tid & 15;
  for (int i = 0; i < 2; ++i)
    for (int j = 0; j < 2; ++j)
      S[(size_t)(m0 + ty * 2 + i) * CTX + n0 + tx * 2 + j] = acc[i][j];
}

// Yt[j][r] = sum_c Et[j][c] * phi[r][c]
__global__ __launch_bounds__(256) void yt_kernel(const unsigned short* __restrict__ Etb,
                                                 const unsigned short* __restrict__ phi5,
                                                 unsigned short* __restrict__ Ytb) {
  int b = blockIdx.z;
  int m0 = blockIdx.y * 64, n0 = blockIdx.x * 64;
  f32x4 acc[2][2]; zero_acc(acc);
  mfma_tile64(Etb + ((size_t)b * Dd + m0) * CTX, CTX,
              phi5 + (size_t)b * CS + (size_t)n0 * CTX, CTX, CTX, acc);
  unsigned short* Y = Ytb + (size_t)b * Dd * CTX;
  int lane = threadIdx.x & 63, w = threadIdx.x >> 6;
  int wr = (w >> 1) & 1, wc = w & 1;
  int l4 = (lane >> 4) << 2, lc = lane & 15;
  for (int mr = 0; mr < 2; ++mr)
    for (int nc = 0; nc < 2; ++nc)
      for (int i = 0; i < 4; ++i) {
        int rr = m0 + wr * 32 + mr * 16 + l4 + i;
        int cc = n0 + wc * 32 + nc * 16 + lc;
        Y[(size_t)rr * CTX + cc] = f2bf(acc[mr][nc][i]);
      }
}

// og = Kt @ Yt^T * s ; fused M update
__global__ __launch_bounds__(256) void og_kernel(const unsigned short* __restrict__ Ktb,
                                                 const unsigned short* __restrict__ Ytb,
                                                 float* __restrict__ Mtf, unsigned short* __restrict__ Mtb,
                                                 const float* __restrict__ etam, const float* __restrict__ alm,
                                                 const float* __restrict__ nrm2, int t) {
  int b = blockIdx.z;
  int m0 = blockIdx.y * 64, n0 = blockIdx.x * 64;
  f32x4 acc[2][2]; zero_acc(acc);
  mfma_tile64(Ktb + ((size_t)b * Dd + m0) * CTX, CTX,
              Ytb + ((size_t)b * Dd + n0) * CTX, CTX, CTX, acc);
  float s = 1.f / (sqrtf(nrm2[t * 4 + b]) + 1e-7f);
  const float* al = alm + ((size_t)b * NCh + t) * Dd;
  const float* et = etam + ((size_t)b * NCh + t) * Dd;
  float* Mf = Mtf + ((size_t)b << 20);
  unsigned short* Mb2 = Mtb + ((size_t)b << 20);
  int lane = threadIdx.x & 63, w = threadIdx.x >> 6;
  int wr = (w >> 1) & 1, wc = w & 1;
  int l4 = (lane >> 4) << 2, lc = lane & 15;
  for (int mr = 0; mr < 2; ++mr)
    for (int nc = 0; nc < 2; ++nc)
      for (int i = 0; i < 4; ++i) {
        int ii = m0 + wr * 32 + mr * 16 + l4 + i;
        int jj = n0 + wc * 32 + nc * 16 + lc;
        size_t idx = ((size_t)jj << 10) + ii;
        float nm = Mf[idx] * al[jj] - et[jj] * (acc[mr][nc][i] * s);
        Mf[idx] = nm; Mb2[idx] = f2bf(nm);
      }
}

// c_out = c_q @ M'  into d_out (pre-norm)
__global__ __launch_bounds__(256) void cout_kernel(const unsigned short* __restrict__ qb,
                                                   const unsigned short* __restrict__ Mtb,
                                                   float* __restrict__ outp, int t) {
  int b = blockIdx.z;
  int n0 = blockIdx.x * 64;
  const unsigned short* A = qb + ((size_t)b * Ss + (size_t)t * CHK) * Dd;
  f32x4 acc[2][2]; zero_acc(acc);
  mfma_tile64(A, Dd, Mtb + ((size_t)b << 20) + (size_t)n0 * Dd, Dd, Dd, acc);
  int lane = threadIdx.x & 63, w = threadIdx.x >> 6;
  int wr = (w >> 1) & 1, wc = w & 1;
  int l4 = (lane >> 4) << 2, lc = lane & 15;
  for (int mr = 0; mr < 2; ++mr)
    for (int nc = 0; nc < 2; ++nc)
      for (int i = 0; i < 4; ++i) {
        int rr = wr * 32 + mr * 16 + l4 + i;
        int cc = n0 + wc * 32 + nc * 16 + lc;
        outp[((size_t)b * Ss + (size_t)t * CHK + rr) * Dd + cc] = acc[mr][nc][i];
      }
}

// =================== post-stage ===================

__global__ __launch_bounds__(256) void final_out_kernel(float* __restrict__ o, const float* __restrict__ w,
                                                        const unsigned short* __restrict__ gb) {
  size_t row = blockIdx.x;
  float* r = o + row * Dd;
  int t = threadIdx.x;
  f32x4 v = *(const f32x4*)(r + t * 4);
  float ss = v[0] * v[0] + v[1] * v[1] + v[2] * v[2] + v[3] * v[3];
  ss = block_sum256(ss);
  float sc = rsqrtf(ss * (1.f / Dd) + EPSf);
  f32x4 wv = *(const f32x4*)(w + t * 4);
  us4 g = *(const us4*)(gb + row * Dd + t * 4);
#pragma unroll
  for (int i = 0; i < 4; ++i)
    r[t * 4 + i] = v[i] * sc * wv[i] * bf2f(g[i]);
}

__global__ __launch_bounds__(256) void final_m_kernel(const float* __restrict__ Mtf, float* __restrict__ outM) {
  size_t idx = (size_t)blockIdx.x * 256 + threadIdx.x; // B*D*D
  int b = (int)(idx >> 20); size_t rem = idx & 1048575;
  int i = (int)(rem >> 10), j = (int)(rem & 1023);
  outM[idx] = Mtf[((size_t)b << 20) + ((size_t)j << 10) + i];
}

__global__ __launch_bounds__(256) void final_buf_kernel(const unsigned short* __restrict__ kext,
                                                        const unsigned short* __restrict__ vext,
                                                        float* __restrict__ dbk, float* __restrict__ dbv) {
  size_t idx = (size_t)blockIdx.x * 256 + threadIdx.x; // B*WIN*D
  int b = (int)(idx >> 17); size_t rem = idx & 131071;
  size_t src = ((size_t)b * SEXT + Ss) * Dd + rem; // rows [4096,4224)
  dbk[idx] = bf2f(kext[src]);
  dbv[idx] = bf2f(vext[src]);
}

// =================== launcher ===================

extern "C" void kernel_launch(void* const* d_in, const int* in_sizes, int n_in,
                              void* d_out, int out_size, void* d_ws, size_t ws_size,
                              hipStream_t stream) {
  (void)in_sizes; (void)n_in; (void)out_size;
  const float* x    = (const float*)d_in[0];
  const float* mem  = (const float*)d_in[1];
  const float* bufk = (const float*)d_in[2];
  const float* bufv = (const float*)d_in[3];
  const float* w_in = (const float*)d_in[4];
  const float* w_kq = (const float*)d_in[5];
  const float* w_out= (const float*)d_in[6];
  const float* Wk   = (const float*)d_in[7];
  const float* Wq   = (const float*)d_in[8];
  const float* Wv   = (const float*)d_in[9];
  const float* Wg   = (const float*)d_in[10];
  const float* Wb   = (const float*)d_in[11];
  const float* ckw  = (const float*)d_in[12];
  const float* ckb  = (const float*)d_in[13];
  const float* cqw  = (const float*)d_in[14];
  const float* cqb  = (const float*)d_in[15];

  float* outp  = (float*)d_out;                          // 64 MiB region
  float* outM  = outp + (size_t)Bb * Ss * Dd;            // 16 MiB region
  float* outBk = outM + (size_t)Bb * Dd * Dd;
  float* outBv = outBk + (size_t)Bb * WIN * Dd;

  // ---- overlays into d_out (re-poisoned scratch each launch):
  // xn (32 MiB bf16) in outp region: dead after bypmul; outp first written by cout (scan).
  // Wall (14 MiB bf16) in outM region: dead after bypmul; outM written by final_m (end).
  unsigned short* xn   = (unsigned short*)outp;
  unsigned short* Wall = (unsigned short*)outM;

  // ---- workspace (~170 MiB) ----
  char* p = (char*)d_ws;
  auto alloc = [&](size_t bytes) -> char* { char* r = p; p += (bytes + 255) & ~(size_t)255; return r; };
  unsigned short* kext = (unsigned short*)alloc((size_t)Bb * SEXT * Dd * 2); // 33 MiB
  unsigned short* vext = (unsigned short*)alloc((size_t)Bb * SEXT * Dd * 2); // 33 MiB (bf16)
  unsigned short* qb   = (unsigned short*)alloc((size_t)Bb * Ss * Dd * 2);   // 32 MiB
  unsigned short* gb   = (unsigned short*)alloc((size_t)Bb * Ss * Dd * 2);   // 32 MiB (gamma*bypass)
  float* etam          = (float*)alloc((size_t)Bb * NCh * Dd * 4);           // 1 MiB
  float* alm           = (float*)alloc((size_t)Bb * NCh * Dd * 4);           // 1 MiB
  float* Mtf           = (float*)alloc((size_t)Bb * Dd * Dd * 4);            // 16 MiB
  unsigned short* Mtb  = (unsigned short*)alloc((size_t)Bb * Dd * Dd * 2);   // 8 MiB
  // shared scratch: halo (8 MiB, pre-stage) then scan temps (~12.9 MiB) — disjoint lifetimes
  char* scratch = alloc((size_t)14 * 1024 * 1024);                           // 14 MiB

  unsigned short* halo = (unsigned short*)scratch;

  char* q = scratch;
  auto allocX = [&](size_t bytes) -> char* { char* r = q; q += (bytes + 255) & ~(size_t)255; return r; };
  float* errf          = (float*)allocX((size_t)Bb * CTX * Dd * 4);          // 3 MiB
  unsigned short* Ktb  = (unsigned short*)allocX((size_t)Bb * Dd * CTX * 2);
  unsigned short* Etb  = (unsigned short*)allocX((size_t)Bb * Dd * CTX * 2);
  unsigned short* Ytb  = (unsigned short*)allocX((size_t)Bb * Dd * CTX * 2);
  float* Tf            = (float*)allocX((size_t)Bb * CS * 4);
  float* Sf            = (float*)allocX((size_t)Bb * CS * 4);
  float* Wf            = (float*)allocX((size_t)Bb * CS * 4);
  float* Wtf           = (float*)allocX((size_t)Bb * CS * 4);
  float* Pf            = (float*)allocX((size_t)Bb * CS * 4);
  float* Zf            = (float*)allocX((size_t)Bb * CS * 4);
  float* Fa            = (float*)allocX((size_t)Bb * CS * 4);
  float* Fb2           = (float*)allocX((size_t)Bb * CS * 4);
  unsigned short* phi5 = (unsigned short*)allocX((size_t)Bb * CS * 2);
  float* nrm2          = (float*)allocX((size_t)NCh * Bb * 4);               // total ~12.9 MiB

  // ---- ws_size guard (diagnostic): if workspace is too small, launch NOTHING.
  // Bench then fails with the empty-output absmax (~29.25) instead of a device
  // fault -> distinguishes "ws too small" from "in-kernel OOB" in one run.
  // Deterministic branch (ws_size constant across calls) -> graph-capture safe.
  size_t ws_needed = (size_t)(p - (char*)d_ws);
  if (ws_size < ws_needed) return;

  // ---- pre-stage (xn in outp region, Wall in outM region until bypmul)
  rmsin_kernel<<<Bb * Ss, 256, 0, stream>>>(x, w_in, xn);
  packw_kernel<<<(7168 * 1024) / 256, 256, 0, stream>>>(Wk, Wq, Wv, Wg, Wb, Wall);
  init_ext_kernel<<<(Bb * WIN * Dd) / 256, 256, 0, stream>>>(bufk, bufv, kext, vext);
  init_mt_kernel<<<(Bb * Dd * Dd) / 256, 256, 0, stream>>>(mem, Mtf, Mtb);
  proj_kernel<<<dim3(6144 / 64, (Bb * Ss) / 64), 256, 0, stream>>>(xn, Wall, kext, qb, vext, gb, etam, alm);
  bypmul_kernel<<<dim3(Dd / 64, (Bb * Ss) / 64), 256, 0, stream>>>(xn, Wall, gb);
  // xn & Wall now dead. halo into scratch; conv in place.
  halo_kernel<<<(Bb * 2 * NCCH * 2 * Dd) / 256, 256, 0, stream>>>(kext, qb, halo);
  conv_ip_kernel<<<dim3(NCCH, 2, Bb), 256, 0, stream>>>(kext, qb, halo, ckw, ckb, cqw, cqb, w_kq);
  zero_nrm_kernel<<<1, NCh * Bb, 0, stream>>>(nrm2);

  // ---- chunked scan (scan temps overwrite dead halo region)
  for (int t = 0; t < NCh; ++t) {
    err_kernel<<<dim3(16, 3, Bb), 256, 0, stream>>>(kext, Mtb, vext, errf, t);
    tnorm_kernel<<<dim3(6, 6, Bb), 256, 0, stream>>>(kext, errf, Tf, Sf, nrm2, t);
    trans_ke_kernel<<<dim3((Dd * CTX) / 256, 1, Bb * 2), 256, 0, stream>>>(kext, errf, Ktb, Etb, t);
    for (int st = 0; st < 5; ++st) {
      ns_wwt_kernel<<<dim3(6, 6, Bb * 2), 256, 0, stream>>>(Sf, Tf, Wf, Wtf, nrm2, t, st);
      ns_p_kernel<<<dim3(6, 6, Bb), 256, 0, stream>>>(Wf, Wtf, Pf);
      const float* Fin = (st & 1) ? Fb2 : Fa;
      float* Fout = (st & 1) ? Fa : Fb2;
      ns_zf_kernel<<<dim3(6, 6, (st < 4) ? Bb * 2 : Bb), 256, 0, stream>>>(Pf, Sf, Fin, Zf, Fout, phi5, nrm2, t, st);
      if (st < 4) ns_snew_kernel<<<dim3(6, 6, Bb), 256, 0, stream>>>(Pf, Zf, Sf);
    }
    yt_kernel<<<dim3(3, 16, Bb), 256, 0, stream>>>(Etb, phi5, Ytb);
    og_kernel<<<dim3(16, 16, Bb), 256, 0, stream>>>(Ktb, Ytb, Mtf, Mtb, etam, alm, nrm2, t);
    cout_kernel<<<dim3(16, 1, Bb), 256, 0, stream>>>(qb, Mtb, outp, t);
  }

  // ---- post-stage (final_m overwrites dead Wall region with real outM)
  final_out_kernel<<<Bb * Ss, 256, 0, stream>>>(outp, w_out, gb);
  final_m_kernel<<<(Bb * Dd * Dd) / 256, 256, 0, stream>>>(Mtf, outM);
  final_buf_kernel<<<(Bb * WIN * Dd) / 256, 256, 0, stream>>>(kext, vext, outBk, outBv);
}